// Round 2
// baseline (438.459 us; speedup 1.0000x reference)
//
#include <hip/hip_runtime.h>

// MHA decode: B=256, NKEYS=2048, EMB=512, H=8, dh=64, f32.
// Memory-bound: must stream key+value (2.148 GB) once -> ~341us floor @6.3TB/s.
// R1: single-pass online softmax. Each 16-lane group keeps (m,l,acc) in
// registers, loads K and V fragments every iteration (2KB/wave-iter in
// flight), no block-wide phase transitions, no score array in LDS.

#define NB    256
#define NK    2048
#define EMBD  512
#define NH    8
#define DH    64

// One block per (b,h). 256 threads = 16 groups of 16 lanes.
// Group g handles keys g, g+16, g+32, ... (block iteration covers 16
// consecutive keys -> 256B coalesced chunks per key row).
__global__ __launch_bounds__(256) void attn_kernel(
    const float* __restrict__ q,
    const float* __restrict__ kptr,
    const float* __restrict__ vptr,
    const int* __restrict__ mask,
    float* __restrict__ merged)
{
    const int bh   = blockIdx.x;
    const int b    = bh >> 3;
    const int h    = bh & 7;
    const int t    = threadIdx.x;
    const int g    = t >> 4;    // group 0..15
    const int li   = t & 15;    // lane within group

    // q fragment: dims li*4 .. li*4+3 of this head
    const float4 q4 = *reinterpret_cast<const float4*>(
        q + (size_t)b * EMBD + h * DH + li * 4);

    const float* kbase = kptr + (size_t)b * NK * EMBD + h * DH + li * 4;
    const float* vbase = vptr + (size_t)b * NK * EMBD + h * DH + li * 4;
    const int*   mrow  = mask + (size_t)b * NK;

    float  m = -1e30f, l = 0.f;
    float4 acc = {0.f, 0.f, 0.f, 0.f};

    #pragma unroll 4
    for (int key = g; key < NK; key += 16) {
        const float4 k4 = *reinterpret_cast<const float4*>(kbase + (size_t)key * EMBD);
        const float4 v4 = *reinterpret_cast<const float4*>(vbase + (size_t)key * EMBD);
        const int    mk = mrow[key];

        float s = q4.x * k4.x + q4.y * k4.y + q4.z * k4.z + q4.w * k4.w;
        // xor butterfly: all 16 lanes end with the full dot product
        s += __shfl_xor(s, 1, 16);
        s += __shfl_xor(s, 2, 16);
        s += __shfl_xor(s, 4, 16);
        s += __shfl_xor(s, 8, 16);
        s *= 0.125f;                       // 1/sqrt(64)

        const float se = mk ? -1e30f : s;  // masked -> effectively -inf
        const float mn = fmaxf(m, se);
        const float r  = __expf(m - mn);   // m=-1e30 start: exp(-big)=0, safe
        const float p  = mk ? 0.f : __expf(s - mn);
        l = l * r + p;
        acc.x = fmaf(acc.x, r, p * v4.x);
        acc.y = fmaf(acc.y, r, p * v4.y);
        acc.z = fmaf(acc.z, r, p * v4.z);
        acc.w = fmaf(acc.w, r, p * v4.w);
        m = mn;
    }

    // merge 16 groups: each group has replicated (m,l) and distributed acc
    __shared__ float sm[16];
    __shared__ float sl[16];
    __shared__ float sacc[16][DH];
    if (li == 0) { sm[g] = m; sl[g] = l; }
    *reinterpret_cast<float4*>(&sacc[g][li * 4]) = acc;
    __syncthreads();

    if (t < DH) {
        float M = sm[0];
        #pragma unroll
        for (int i = 1; i < 16; ++i) M = fmaxf(M, sm[i]);
        float L = 0.f, o = 0.f;
        #pragma unroll
        for (int i = 0; i < 16; ++i) {
            const float f = __expf(sm[i] - M);
            L += f * sl[i];
            o += f * sacc[i][t];
        }
        merged[(size_t)b * EMBD + h * DH + t] = o / L;
    }
}

// out[b,j] = sum_i merged[b,i] * Wo[j,i].  Wo is 1MB -> L2 resident.
// Safe when merged aliases out: row b staged to LDS + barrier before writes.
__global__ __launch_bounds__(256) void proj_kernel(
    const float* __restrict__ merged,
    const float* __restrict__ Wo,
    float* __restrict__ out)
{
    const int b = blockIdx.x;
    const int t = threadIdx.x;
    __shared__ float mrow[EMBD];
    *reinterpret_cast<float2*>(&mrow[t * 2]) =
        *reinterpret_cast<const float2*>(&merged[(size_t)b * EMBD + t * 2]);
    __syncthreads();

    const float4* mv = reinterpret_cast<const float4*>(mrow);
    #pragma unroll
    for (int half = 0; half < 2; ++half) {
        const int j = t + half * 256;
        const float4* wrow = reinterpret_cast<const float4*>(Wo + (size_t)j * EMBD);
        float s = 0.f;
        #pragma unroll 4
        for (int i = 0; i < EMBD / 4; ++i) {
            const float4 wv = wrow[i];
            const float4 qv = mv[i];
            s += wv.x * qv.x + wv.y * qv.y + wv.z * qv.z + wv.w * qv.w;
        }
        out[(size_t)b * EMBD + j] = s;
    }
}

extern "C" void kernel_launch(void* const* d_in, const int* in_sizes, int n_in,
                              void* d_out, int out_size, void* d_ws, size_t ws_size,
                              hipStream_t stream) {
    const float* q    = (const float*)d_in[0];
    const float* kptr = (const float*)d_in[1];
    const float* vptr = (const float*)d_in[2];
    const float* Wo   = (const float*)d_in[3];
    const int*   mask = (const int*)d_in[4];
    float* out = (float*)d_out;

    float* merged = (ws_size >= (size_t)NB * EMBD * sizeof(float))
                        ? (float*)d_ws : out;

    attn_kernel<<<NB * NH, 256, 0, stream>>>(q, kptr, vptr, mask, merged);
    proj_kernel<<<NB, 256, 0, stream>>>(merged, Wo, out);
}

// Round 3
// 403.335 us; speedup vs baseline: 1.0871x; 1.0871x over previous
//
#include <hip/hip_runtime.h>

// MHA decode: B=256, NKEYS=2048, EMB=512, H=8, dh=64, f32.
// Memory-bound: stream key+value (2.148 GB) once -> ~341us floor @6.3TB/s.
// R2: R0 two-pass skeleton + mask folded into score pass + V prefetch kept
// in flight across lgkm-only barriers in the softmax phase + tiled proj.

#define NB    256
#define NK    2048
#define EMBD  512
#define NH    8
#define DH    64

// lgkm-only barrier: LDS producer/consumer safe (each wave drains its own
// ds ops before arriving), but does NOT drain vmcnt -> global loads issued
// before it stay in flight (8-phase-template pattern).
__device__ __forceinline__ void barrier_lgkm() {
    asm volatile("s_waitcnt lgkmcnt(0)" ::: "memory");
    __builtin_amdgcn_s_barrier();
}

// One block per (b,h). 256 threads = 16 groups of 16 lanes; group handles
// one key per block-iteration with float4 loads (16x16B=256B coalesced).
__global__ __launch_bounds__(256) void attn_kernel(
    const float* __restrict__ q,
    const float* __restrict__ kptr,
    const float* __restrict__ vptr,
    const int* __restrict__ mask,
    float* __restrict__ merged)
{
    const int bh   = blockIdx.x;
    const int b    = bh >> 3;
    const int h    = bh & 7;
    const int t    = threadIdx.x;
    const int lane = t & 63;
    const int w    = t >> 6;       // wave 0..3
    const int grp  = lane >> 4;    // group 0..3 within wave
    const int li   = lane & 15;    // lane within group

    __shared__ float sc[NK];       // masked scores -> exp(p) (8KB)
    __shared__ float redm[4];
    __shared__ float redl[4];
    __shared__ float ored[4 * DH];

    const float4 q4 = *reinterpret_cast<const float4*>(
        q + (size_t)b * EMBD + h * DH + li * 4);
    const float* kbase = kptr + (size_t)b * NK * EMBD + h * DH + li * 4;
    const float* vbase = vptr + (size_t)b * NK * EMBD + h * DH + li * 4;
    const int*   mrow  = mask + (size_t)b * NK;
    const int    key0  = w * 4 + grp;

    // ---- score pass: K stream, mask folded in ----
    #pragma unroll 4
    for (int it = 0; it < NK / 16; ++it) {
        const int key = it * 16 + key0;
        const float4 k4 = *reinterpret_cast<const float4*>(
            kbase + (size_t)key * EMBD);
        float s = q4.x * k4.x + q4.y * k4.y + q4.z * k4.z + q4.w * k4.w;
        s += __shfl_xor(s, 1, 16);
        s += __shfl_xor(s, 2, 16);
        s += __shfl_xor(s, 4, 16);
        s += __shfl_xor(s, 8, 16);
        if (li == 0) sc[key] = mrow[key] ? -1e30f : s * 0.125f;
    }

    // prefetch first two V fragments; they stay in flight across the
    // whole softmax phase (no vmcnt drain at lgkm-only barriers).
    float4 pv0 = *reinterpret_cast<const float4*>(vbase + (size_t)key0 * EMBD);
    float4 pv1 = *reinterpret_cast<const float4*>(vbase + (size_t)(key0 + 16) * EMBD);

    barrier_lgkm();

    // ---- block max (raw masked scores; -1e30 entries never win) ----
    float lmax = -INFINITY;
    #pragma unroll
    for (int i = 0; i < 8; ++i) lmax = fmaxf(lmax, sc[t + 256 * i]);
    #pragma unroll
    for (int off = 32; off >= 1; off >>= 1)
        lmax = fmaxf(lmax, __shfl_xor(lmax, off, 64));
    if (lane == 0) redm[w] = lmax;
    barrier_lgkm();
    const float m = fmaxf(fmaxf(redm[0], redm[1]), fmaxf(redm[2], redm[3]));

    // ---- exp + denom (pure LDS/VALU; masked -> exp underflows to 0) ----
    float lsum = 0.f;
    #pragma unroll
    for (int i = 0; i < 8; ++i) {
        const int kk = t + 256 * i;
        const float p = __expf(sc[kk] - m);
        sc[kk] = p;
        lsum += p;
    }
    #pragma unroll
    for (int off = 32; off >= 1; off >>= 1) lsum += __shfl_xor(lsum, off, 64);
    if (lane == 0) redl[w] = lsum;
    barrier_lgkm();

    // ---- V accumulation with 2-deep rotation ----
    float4 acc = {0.f, 0.f, 0.f, 0.f};
    for (int it = 0; it < NK / 16; ++it) {
        const int key = it * 16 + key0;
        const float4 cur = pv0;
        pv0 = pv1;
        if (it < NK / 16 - 2)
            pv1 = *reinterpret_cast<const float4*>(vbase + (size_t)(key + 32) * EMBD);
        const float p = sc[key];   // broadcast within group
        acc.x = fmaf(p, cur.x, acc.x);
        acc.y = fmaf(p, cur.y, acc.y);
        acc.z = fmaf(p, cur.z, acc.z);
        acc.w = fmaf(p, cur.w, acc.w);
    }
    #pragma unroll
    for (int off = 16; off <= 32; off <<= 1) {
        acc.x += __shfl_xor(acc.x, off, 64);
        acc.y += __shfl_xor(acc.y, off, 64);
        acc.z += __shfl_xor(acc.z, off, 64);
        acc.w += __shfl_xor(acc.w, off, 64);
    }
    if (lane < 16) *reinterpret_cast<float4*>(&ored[w * DH + li * 4]) = acc;
    barrier_lgkm();
    if (t < DH) {
        const float denom = redl[0] + redl[1] + redl[2] + redl[3];
        const float o = (ored[t] + ored[DH + t] + ored[2 * DH + t] + ored[3 * DH + t]) / denom;
        merged[(size_t)b * EMBD + h * DH + t] = o;
    }
}

// Tiled projection: block = 8 batches x 64 j's. W_o logical traffic
// drops 256MB -> 32MB (L2-resident). NOT in-place safe.
__global__ __launch_bounds__(256) void proj_kernel_split(
    const float* __restrict__ merged,
    const float* __restrict__ Wo,
    float* __restrict__ out)
{
    const int bt = blockIdx.x >> 3;   // batch tile 0..31 (8 batches each)
    const int jt = blockIdx.x & 7;    // j tile 0..7 (64 outputs each)
    const int t  = threadIdx.x;
    __shared__ float4 mrow[8 * 128];  // 8 rows x 512 floats = 16KB
    #pragma unroll
    for (int k = 0; k < 4; ++k) {
        const int idx = k * 256 + t;
        mrow[idx] = reinterpret_cast<const float4*>(
            merged + (size_t)bt * 8 * EMBD)[idx];
    }
    __syncthreads();

    const int j    = jt * 64 + (t & 63);
    const int brel = t >> 6;          // one brel per wave -> LDS broadcast
    const float4* wrow = reinterpret_cast<const float4*>(Wo + (size_t)j * EMBD);
    const float4* m0 = &mrow[brel * 128];
    const float4* m1 = &mrow[(brel + 4) * 128];
    float s0 = 0.f, s1 = 0.f;
    #pragma unroll 4
    for (int i = 0; i < 128; ++i) {
        const float4 wv = wrow[i];
        const float4 a0 = m0[i];
        const float4 a1 = m1[i];
        s0 += wv.x * a0.x + wv.y * a0.y + wv.z * a0.z + wv.w * a0.w;
        s1 += wv.x * a1.x + wv.y * a1.y + wv.z * a1.z + wv.w * a1.w;
    }
    out[(size_t)(bt * 8 + brel) * EMBD + j] = s0;
    out[(size_t)(bt * 8 + brel + 4) * EMBD + j] = s1;
}

// In-place-safe fallback (merged aliases out): one block per batch row,
// stage row to LDS, barrier, then overwrite.
__global__ __launch_bounds__(256) void proj_kernel_inplace(
    const float* __restrict__ merged,
    const float* __restrict__ Wo,
    float* __restrict__ out)
{
    const int b = blockIdx.x;
    const int t = threadIdx.x;
    __shared__ float mrow[EMBD];
    *reinterpret_cast<float2*>(&mrow[t * 2]) =
        *reinterpret_cast<const float2*>(&merged[(size_t)b * EMBD + t * 2]);
    __syncthreads();

    const float4* mv = reinterpret_cast<const float4*>(mrow);
    #pragma unroll
    for (int half = 0; half < 2; ++half) {
        const int j = t + half * 256;
        const float4* wrow = reinterpret_cast<const float4*>(Wo + (size_t)j * EMBD);
        float s = 0.f;
        #pragma unroll 4
        for (int i = 0; i < EMBD / 4; ++i) {
            const float4 wv = wrow[i];
            const float4 qv = mv[i];
            s += wv.x * qv.x + wv.y * qv.y + wv.z * qv.z + wv.w * qv.w;
        }
        out[(size_t)b * EMBD + j] = s;
    }
}

extern "C" void kernel_launch(void* const* d_in, const int* in_sizes, int n_in,
                              void* d_out, int out_size, void* d_ws, size_t ws_size,
                              hipStream_t stream) {
    const float* q    = (const float*)d_in[0];
    const float* kptr = (const float*)d_in[1];
    const float* vptr = (const float*)d_in[2];
    const float* Wo   = (const float*)d_in[3];
    const int*   mask = (const int*)d_in[4];
    float* out = (float*)d_out;

    float* merged = (ws_size >= (size_t)NB * EMBD * sizeof(float))
                        ? (float*)d_ws : out;

    attn_kernel<<<NB * NH, 256, 0, stream>>>(q, kptr, vptr, mask, merged);
    if (merged != out)
        proj_kernel_split<<<NB, 256, 0, stream>>>(merged, Wo, out);
    else
        proj_kernel_inplace<<<NB, 256, 0, stream>>>(merged, Wo, out);
}

// Round 4
// 383.145 us; speedup vs baseline: 1.1444x; 1.0527x over previous
//
#include <hip/hip_runtime.h>

// MHA decode: B=256, NKEYS=2048, EMB=512, H=8, dh=64, f32.
// Memory-bound: stream key+value (2.148 GB) once -> ~341us floor @6.3TB/s.
// R3: one block per BATCH (not per head). A wave reads the full 2KB K/V row
// (all 8 heads) -> block slides a dense 32KB window through K[b] then V[b],
// matching the sequential-stream pattern that hits 6.3TB/s. Scores for all
// 8 heads kept in LDS [8][2052]. Mask+V prefetched into regs across the
// softmax phase; barriers are lgkm-only (loads stay in flight).

#define NB    256
#define NK    2048
#define EMBD  512
#define NH    8
#define DH    64
#define SCP   2052   // score row stride (floats): h*2052%32 = 4h -> distinct banks
#define ACP   520    // acc row stride for the final reduce

__device__ __forceinline__ void barrier_lgkm() {
    asm volatile("s_waitcnt lgkmcnt(0)" ::: "memory");
    __builtin_amdgcn_s_barrier();
}

__device__ __forceinline__ float4 ld4(const float* p) {
    return *reinterpret_cast<const float4*>(p);
}

// 1024 threads = 16 waves. Wave w handles keys {it*16+w}. Lane l owns the
// 32B slice [l*8, l*8+8) of each 512-float row -> head h = l>>3.
__global__ __launch_bounds__(1024) void attn_kernel(
    const float* __restrict__ q,
    const float* __restrict__ kptr,
    const float* __restrict__ vptr,
    const int* __restrict__ mask,
    float* __restrict__ merged)
{
    const int b    = blockIdx.x;
    const int t    = threadIdx.x;
    const int w    = t >> 6;        // wave 0..15
    const int lane = t & 63;
    const int hq   = lane >> 3;     // head of this lane's row slice
    const int sub  = lane & 7;

    __shared__ float sc[NH][SCP];   // 65.7KB: scores -> p values
    __shared__ float redm[16], redl[16];

    const float* qb = q + (size_t)b * EMBD + lane * 8;
    const float4 qa = ld4(qb);
    const float4 qc = ld4(qb + 4);
    const float* kb = kptr + (size_t)b * NK * EMBD + lane * 8;
    const float* vb = vptr + (size_t)b * NK * EMBD + lane * 8;
    const int*   mrow = mask + (size_t)b * NK;

    // ---- score pass: dense K stream ----
    #pragma unroll 2
    for (int it = 0; it < NK / 16; ++it) {
        const int key = it * 16 + w;
        const float* kk = kb + (size_t)key * EMBD;
        const float4 ka = ld4(kk);
        const float4 kc = ld4(kk + 4);
        float s = qa.x * ka.x + qa.y * ka.y + qa.z * ka.z + qa.w * ka.w
                + qc.x * kc.x + qc.y * kc.y + qc.z * kc.z + qc.w * kc.w;
        // segmented sum over the 8 lanes of this head group
        s += __shfl_xor(s, 1, 8);
        s += __shfl_xor(s, 2, 8);
        s += __shfl_xor(s, 4, 8);
        if (sub == 0) sc[hq][key] = s * 0.125f;   // 1/sqrt(64)
    }

    // softmax thread mapping: 2 waves per head; tl = 0..127 within head
    const int hh = w >> 1;
    const int tl = ((w & 1) << 6) | lane;

    // prefetch mask (regs) + 2-deep V; stay in flight across lgkm barriers
    int mk[16];
    #pragma unroll
    for (int j = 0; j < 16; ++j) mk[j] = mrow[j * 128 + tl];
    float4 p0a = ld4(vb + (size_t)w * EMBD);
    float4 p0c = ld4(vb + (size_t)w * EMBD + 4);
    float4 p1a = ld4(vb + (size_t)(w + 16) * EMBD);
    float4 p1c = ld4(vb + (size_t)(w + 16) * EMBD + 4);

    barrier_lgkm();   // scores visible

    // ---- block max per head (raw scores; >= masked max, numerically safe) ----
    float lm = -INFINITY;
    #pragma unroll
    for (int j = 0; j < 16; ++j) lm = fmaxf(lm, sc[hh][j * 128 + tl]);
    #pragma unroll
    for (int off = 32; off >= 1; off >>= 1)
        lm = fmaxf(lm, __shfl_xor(lm, off, 64));
    if (lane == 0) redm[w] = lm;
    barrier_lgkm();
    const float m = fmaxf(redm[hh * 2], redm[hh * 2 + 1]);

    // ---- exp + mask + denom (each element owned by exactly one thread) ----
    float ls = 0.f;
    #pragma unroll
    for (int j = 0; j < 16; ++j) {
        const int kk2 = j * 128 + tl;
        const float p = mk[j] ? 0.f : __expf(sc[hh][kk2] - m);
        sc[hh][kk2] = p;
        ls += p;
    }
    #pragma unroll
    for (int off = 32; off >= 1; off >>= 1) ls += __shfl_xor(ls, off, 64);
    if (lane == 0) redl[w] = ls;
    barrier_lgkm();   // p values + partial denoms visible

    // ---- V pass: dense V stream with 2-deep rotation ----
    float4 a0 = {0.f, 0.f, 0.f, 0.f};
    float4 a1 = {0.f, 0.f, 0.f, 0.f};
    for (int it = 0; it < NK / 16; ++it) {
        const int key = it * 16 + w;
        const float4 va = p0a, vc = p0c;
        p0a = p1a; p0c = p1c;
        if (it < NK / 16 - 2) {
            p1a = ld4(vb + (size_t)(key + 32) * EMBD);
            p1c = ld4(vb + (size_t)(key + 32) * EMBD + 4);
        }
        const float p = sc[hq][key];   // 8 banks, broadcast within group
        a0.x = fmaf(p, va.x, a0.x); a0.y = fmaf(p, va.y, a0.y);
        a0.z = fmaf(p, va.z, a0.z); a0.w = fmaf(p, va.w, a0.w);
        a1.x = fmaf(p, vc.x, a1.x); a1.y = fmaf(p, vc.y, a1.y);
        a1.z = fmaf(p, vc.z, a1.z); a1.w = fmaf(p, vc.w, a1.w);
    }

    barrier_lgkm();   // all sc reads done -> safe to reuse as acc buffer
    float* accb = &sc[0][0];
    *reinterpret_cast<float4*>(&accb[w * ACP + lane * 8])     = a0;
    *reinterpret_cast<float4*>(&accb[w * ACP + lane * 8 + 4]) = a1;
    barrier_lgkm();

    if (t < EMBD) {
        float s = 0.f;
        #pragma unroll
        for (int ww = 0; ww < 16; ++ww) s += accb[ww * ACP + t];
        const int h = t >> 6;
        const float den = redl[h * 2] + redl[h * 2 + 1];
        merged[(size_t)b * EMBD + t] = s / den;
    }
}

// Tiled projection: block = 8 batches x 64 j's (W_o stays L2-resident).
__global__ __launch_bounds__(256) void proj_kernel_split(
    const float* __restrict__ merged,
    const float* __restrict__ Wo,
    float* __restrict__ out)
{
    const int bt = blockIdx.x >> 3;
    const int jt = blockIdx.x & 7;
    const int t  = threadIdx.x;
    __shared__ float4 mrow[8 * 128];
    #pragma unroll
    for (int k = 0; k < 4; ++k) {
        const int idx = k * 256 + t;
        mrow[idx] = reinterpret_cast<const float4*>(
            merged + (size_t)bt * 8 * EMBD)[idx];
    }
    __syncthreads();

    const int j    = jt * 64 + (t & 63);
    const int brel = t >> 6;
    const float4* wrow = reinterpret_cast<const float4*>(Wo + (size_t)j * EMBD);
    const float4* m0 = &mrow[brel * 128];
    const float4* m1 = &mrow[(brel + 4) * 128];
    float s0 = 0.f, s1 = 0.f;
    #pragma unroll 4
    for (int i = 0; i < 128; ++i) {
        const float4 wv = wrow[i];
        const float4 x0 = m0[i];
        const float4 x1 = m1[i];
        s0 += wv.x * x0.x + wv.y * x0.y + wv.z * x0.z + wv.w * x0.w;
        s1 += wv.x * x1.x + wv.y * x1.y + wv.z * x1.z + wv.w * x1.w;
    }
    out[(size_t)(bt * 8 + brel) * EMBD + j] = s0;
    out[(size_t)(bt * 8 + brel + 4) * EMBD + j] = s1;
}

// In-place-safe fallback (merged aliases out).
__global__ __launch_bounds__(256) void proj_kernel_inplace(
    const float* __restrict__ merged,
    const float* __restrict__ Wo,
    float* __restrict__ out)
{
    const int b = blockIdx.x;
    const int t = threadIdx.x;
    __shared__ float mrow[EMBD];
    *reinterpret_cast<float2*>(&mrow[t * 2]) =
        *reinterpret_cast<const float2*>(&merged[(size_t)b * EMBD + t * 2]);
    __syncthreads();

    const float4* mv = reinterpret_cast<const float4*>(mrow);
    #pragma unroll
    for (int half = 0; half < 2; ++half) {
        const int j = t + half * 256;
        const float4* wrow = reinterpret_cast<const float4*>(Wo + (size_t)j * EMBD);
        float s = 0.f;
        #pragma unroll 4
        for (int i = 0; i < EMBD / 4; ++i) {
            const float4 wv = wrow[i];
            const float4 qv = mv[i];
            s += wv.x * qv.x + wv.y * qv.y + wv.z * qv.z + wv.w * qv.w;
        }
        out[(size_t)b * EMBD + j] = s;
    }
}

extern "C" void kernel_launch(void* const* d_in, const int* in_sizes, int n_in,
                              void* d_out, int out_size, void* d_ws, size_t ws_size,
                              hipStream_t stream) {
    const float* q    = (const float*)d_in[0];
    const float* kptr = (const float*)d_in[1];
    const float* vptr = (const float*)d_in[2];
    const float* Wo   = (const float*)d_in[3];
    const int*   mask = (const int*)d_in[4];
    float* out = (float*)d_out;

    float* merged = (ws_size >= (size_t)NB * EMBD * sizeof(float))
                        ? (float*)d_ws : out;

    attn_kernel<<<NB, 1024, 0, stream>>>(q, kptr, vptr, mask, merged);
    if (merged != out)
        proj_kernel_split<<<NB, 256, 0, stream>>>(merged, Wo, out);
    else
        proj_kernel_inplace<<<NB, 256, 0, stream>>>(merged, Wo, out);
}

// Round 5
// 259.407 us; speedup vs baseline: 1.6902x; 1.4770x over previous
//
#include <hip/hip_runtime.h>

// MHA decode: B=256, NKEYS=2048, EMB=512, H=8, dh=64, f32.
// R4: mask-aware load skipping. ~50% of keys are masked (randint(0,2)==1);
// masked keys need NEITHER their K row NOR their V row. One wave owns one
// whole 2KB key row -> mask[key] is wave-uniform -> clean uniform branch
// skips aligned 2KB rows. Real traffic 2.148GB -> ~1.08GB.
// Keeps R3 structure: one block per batch, dense full-row streaming,
// scores for all 8 heads in LDS, lgkm-only barriers.

#define NB    256
#define NK    2048
#define EMBD  512
#define NH    8
#define DH    64
#define SCP   2052   // score row stride: (4h+key)%32 -> heads hit distinct banks
#define ACP   520    // acc row stride for the final reduce

__device__ __forceinline__ void barrier_lgkm() {
    asm volatile("s_waitcnt lgkmcnt(0)" ::: "memory");
    __builtin_amdgcn_s_barrier();
}

__device__ __forceinline__ float4 ld4(const float* p) {
    return *reinterpret_cast<const float4*>(p);
}

// 1024 threads = 16 waves. Wave w handles keys {it*16+w}. Lane l owns the
// 32B slice [l*8, l*8+8) of each 512-float row -> head h = l>>3.
__global__ __launch_bounds__(1024) void attn_kernel(
    const float* __restrict__ q,
    const float* __restrict__ kptr,
    const float* __restrict__ vptr,
    const int* __restrict__ mask,
    float* __restrict__ merged)
{
    const int b    = blockIdx.x;
    const int t    = threadIdx.x;
    const int w    = t >> 6;        // wave 0..15
    const int lane = t & 63;
    const int hq   = lane >> 3;     // head of this lane's row slice
    const int sub  = lane & 7;

    __shared__ float sc[NH][SCP];   // 65.7KB: scores -> p values
    __shared__ int   smask[NK];     // 8KB: per-key mask flag for the V pass
    __shared__ float redm[16], redl[16];

    const float* qb = q + (size_t)b * EMBD + lane * 8;
    const float4 qa = ld4(qb);
    const float4 qc = ld4(qb + 4);
    const float* kb = kptr + (size_t)b * NK * EMBD + lane * 8;
    const float* vb = vptr + (size_t)b * NK * EMBD + lane * 8;
    const int*   mrow = mask + (size_t)b * NK;

    // ---- score pass: dense K stream, masked rows skipped entirely ----
    #pragma unroll 2
    for (int it = 0; it < NK / 16; ++it) {
        const int key = it * 16 + w;
        const int mk  = mrow[key];          // wave-uniform -> scalar/broadcast
        if (lane == 0) smask[key] = mk;
        if (mk) {
            if (sub == 0) sc[hq][key] = -1e30f;  // exp underflows to 0 later
        } else {
            const float* kk = kb + (size_t)key * EMBD;
            const float4 ka = ld4(kk);
            const float4 kc = ld4(kk + 4);
            float s = qa.x * ka.x + qa.y * ka.y + qa.z * ka.z + qa.w * ka.w
                    + qc.x * kc.x + qc.y * kc.y + qc.z * kc.z + qc.w * kc.w;
            // segmented sum over the 8 lanes of this head group
            s += __shfl_xor(s, 1, 8);
            s += __shfl_xor(s, 2, 8);
            s += __shfl_xor(s, 4, 8);
            if (sub == 0) sc[hq][key] = s * 0.125f;   // 1/sqrt(64)
        }
    }

    // softmax thread mapping: 2 waves per head; tl = 0..127 within head
    const int hh = w >> 1;
    const int tl = ((w & 1) << 6) | lane;

    barrier_lgkm();   // scores + smask visible

    // ---- block max per head (masked entries are -1e30, never win) ----
    float lm = -INFINITY;
    #pragma unroll
    for (int j = 0; j < 16; ++j) lm = fmaxf(lm, sc[hh][j * 128 + tl]);
    #pragma unroll
    for (int off = 32; off >= 1; off >>= 1)
        lm = fmaxf(lm, __shfl_xor(lm, off, 64));
    if (lane == 0) redm[w] = lm;
    barrier_lgkm();
    const float m = fmaxf(redm[hh * 2], redm[hh * 2 + 1]);

    // ---- exp + denom (masked: exp(-1e30 - m) == 0, no branch needed) ----
    float ls = 0.f;
    #pragma unroll
    for (int j = 0; j < 16; ++j) {
        const int kk2 = j * 128 + tl;
        const float p = __expf(sc[hh][kk2] - m);
        sc[hh][kk2] = p;
        ls += p;
    }
    #pragma unroll
    for (int off = 32; off >= 1; off >>= 1) ls += __shfl_xor(ls, off, 64);
    if (lane == 0) redl[w] = ls;
    barrier_lgkm();   // p values + partial denoms visible

    // ---- V pass: dense V stream, masked rows skipped entirely ----
    float4 a0 = {0.f, 0.f, 0.f, 0.f};
    float4 a1 = {0.f, 0.f, 0.f, 0.f};
    #pragma unroll 2
    for (int it = 0; it < NK / 16; ++it) {
        const int key = it * 16 + w;
        if (!smask[key]) {                  // wave-uniform LDS broadcast
            const float* vv = vb + (size_t)key * EMBD;
            const float4 va = ld4(vv);
            const float4 vc = ld4(vv + 4);
            const float p = sc[hq][key];    // distinct banks across heads
            a0.x = fmaf(p, va.x, a0.x); a0.y = fmaf(p, va.y, a0.y);
            a0.z = fmaf(p, va.z, a0.z); a0.w = fmaf(p, va.w, a0.w);
            a1.x = fmaf(p, vc.x, a1.x); a1.y = fmaf(p, vc.y, a1.y);
            a1.z = fmaf(p, vc.z, a1.z); a1.w = fmaf(p, vc.w, a1.w);
        }
    }

    barrier_lgkm();   // all sc reads done -> safe to reuse as acc buffer
    float* accb = &sc[0][0];
    *reinterpret_cast<float4*>(&accb[w * ACP + lane * 8])     = a0;
    *reinterpret_cast<float4*>(&accb[w * ACP + lane * 8 + 4]) = a1;
    barrier_lgkm();

    if (t < EMBD) {
        float s = 0.f;
        #pragma unroll
        for (int ww = 0; ww < 16; ++ww) s += accb[ww * ACP + t];
        const int h = t >> 6;
        const float den = redl[h * 2] + redl[h * 2 + 1];
        merged[(size_t)b * EMBD + t] = s / den;
    }
}

// Tiled projection: block = 8 batches x 64 j's (W_o stays L2-resident).
__global__ __launch_bounds__(256) void proj_kernel_split(
    const float* __restrict__ merged,
    const float* __restrict__ Wo,
    float* __restrict__ out)
{
    const int bt = blockIdx.x >> 3;
    const int jt = blockIdx.x & 7;
    const int t  = threadIdx.x;
    __shared__ float4 mrow[8 * 128];
    #pragma unroll
    for (int k = 0; k < 4; ++k) {
        const int idx = k * 256 + t;
        mrow[idx] = reinterpret_cast<const float4*>(
            merged + (size_t)bt * 8 * EMBD)[idx];
    }
    __syncthreads();

    const int j    = jt * 64 + (t & 63);
    const int brel = t >> 6;
    const float4* wrow = reinterpret_cast<const float4*>(Wo + (size_t)j * EMBD);
    const float4* m0 = &mrow[brel * 128];
    const float4* m1 = &mrow[(brel + 4) * 128];
    float s0 = 0.f, s1 = 0.f;
    #pragma unroll 4
    for (int i = 0; i < 128; ++i) {
        const float4 wv = wrow[i];
        const float4 x0 = m0[i];
        const float4 x1 = m1[i];
        s0 += wv.x * x0.x + wv.y * x0.y + wv.z * x0.z + wv.w * x0.w;
        s1 += wv.x * x1.x + wv.y * x1.y + wv.z * x1.z + wv.w * x1.w;
    }
    out[(size_t)(bt * 8 + brel) * EMBD + j] = s0;
    out[(size_t)(bt * 8 + brel + 4) * EMBD + j] = s1;
}

// In-place-safe fallback (merged aliases out).
__global__ __launch_bounds__(256) void proj_kernel_inplace(
    const float* __restrict__ merged,
    const float* __restrict__ Wo,
    float* __restrict__ out)
{
    const int b = blockIdx.x;
    const int t = threadIdx.x;
    __shared__ float mrow[EMBD];
    *reinterpret_cast<float2*>(&mrow[t * 2]) =
        *reinterpret_cast<const float2*>(&merged[(size_t)b * EMBD + t * 2]);
    __syncthreads();

    const float4* mv = reinterpret_cast<const float4*>(mrow);
    #pragma unroll
    for (int half = 0; half < 2; ++half) {
        const int j = t + half * 256;
        const float4* wrow = reinterpret_cast<const float4*>(Wo + (size_t)j * EMBD);
        float s = 0.f;
        #pragma unroll 4
        for (int i = 0; i < EMBD / 4; ++i) {
            const float4 wv = wrow[i];
            const float4 qv = mv[i];
            s += wv.x * qv.x + wv.y * qv.y + wv.z * qv.z + wv.w * qv.w;
        }
        out[(size_t)b * EMBD + j] = s;
    }
}

extern "C" void kernel_launch(void* const* d_in, const int* in_sizes, int n_in,
                              void* d_out, int out_size, void* d_ws, size_t ws_size,
                              hipStream_t stream) {
    const float* q    = (const float*)d_in[0];
    const float* kptr = (const float*)d_in[1];
    const float* vptr = (const float*)d_in[2];
    const float* Wo   = (const float*)d_in[3];
    const int*   mask = (const int*)d_in[4];
    float* out = (float*)d_out;

    float* merged = (ws_size >= (size_t)NB * EMBD * sizeof(float))
                        ? (float*)d_ws : out;

    attn_kernel<<<NB, 1024, 0, stream>>>(q, kptr, vptr, mask, merged);
    if (merged != out)
        proj_kernel_split<<<NB, 256, 0, stream>>>(merged, Wo, out);
    else
        proj_kernel_inplace<<<NB, 256, 0, stream>>>(merged, Wo, out);
}

// Round 6
// 208.339 us; speedup vs baseline: 2.1045x; 1.2451x over previous
//
#include <hip/hip_runtime.h>

// MHA decode: B=256, NKEYS=2048, EMB=512, H=8, dh=64, f32.
// R5: R4 (mask-aware 2KB-row skipping, ~1.08GB traffic) + ballot-compacted
// key list so every wave processes ceil(nun/16) rows per pass -> no
// straggler stall at the block barriers (was ~15%: max of 16 Binomial(128,.5)
// ~= 74 vs mean 64). Scores pre-init to -1e30: masked keys branchless
// downstream (exp underflows to 0).

#define NB    256
#define NK    2048
#define EMBD  512
#define NH    8
#define DH    64
#define SCP   2052   // score row stride: (4h+key)%32 -> heads hit distinct banks
#define ACP   520    // acc row stride for the final reduce

__device__ __forceinline__ void barrier_lgkm() {
    asm volatile("s_waitcnt lgkmcnt(0)" ::: "memory");
    __builtin_amdgcn_s_barrier();
}

__device__ __forceinline__ float4 ld4(const float* p) {
    return *reinterpret_cast<const float4*>(p);
}

// 1024 threads = 16 waves. Lane l owns the 32B slice [l*8, l*8+8) of each
// 512-float K/V row -> head h = l>>3. Waves pull rows from the compacted
// unmasked-key list in stride-16 slots.
__global__ __launch_bounds__(1024) void attn_kernel(
    const float* __restrict__ q,
    const float* __restrict__ kptr,
    const float* __restrict__ vptr,
    const int* __restrict__ mask,
    float* __restrict__ merged)
{
    const int b    = blockIdx.x;
    const int t    = threadIdx.x;
    const int w    = t >> 6;        // wave 0..15
    const int lane = t & 63;
    const int hq   = lane >> 3;     // head of this lane's row slice
    const int sub  = lane & 7;

    __shared__ float sc[NH][SCP];   // 65.7KB: scores -> p values
    __shared__ int   klist[NK];     // 8KB: compacted unmasked key ids
    __shared__ int   wavecnt[16];
    __shared__ float redm[16], redl[16];

    const float* qb = q + (size_t)b * EMBD + lane * 8;
    const float4 qa = ld4(qb);
    const float4 qc = ld4(qb + 4);
    const float* kb = kptr + (size_t)b * NK * EMBD + lane * 8;
    const float* vb = vptr + (size_t)b * NK * EMBD + lane * 8;
    const int*   mrow = mask + (size_t)b * NK;

    // ---- phase 0a: ballot-count unmasked keys + init all scores to -1e30 ----
    const int kA = w * 128 + lane;        // wave w owns keys [w*128, w*128+128)
    const int kB = kA + 64;
    const int mA = mrow[kA];
    const int mB = mrow[kB];
    const unsigned long long balA = __ballot(mA == 0);
    const unsigned long long balB = __ballot(mB == 0);
    if (lane == 0) wavecnt[w] = __popcll(balA) + __popcll(balB);
    float4* scf = reinterpret_cast<float4*>(&sc[0][0]);
    #pragma unroll
    for (int i = 0; i < 5; ++i) {
        const int idx = i * 1024 + t;
        if (idx < (NH * SCP) / 4)
            scf[idx] = make_float4(-1e30f, -1e30f, -1e30f, -1e30f);
    }
    barrier_lgkm();

    // ---- phase 0b: offsets (tiny redundant scan) + compact write ----
    int off = 0, nun = 0;
    #pragma unroll
    for (int i = 0; i < 16; ++i) {
        const int c = wavecnt[i];
        off += (i < w) ? c : 0;
        nun += c;
    }
    const unsigned long long below = (1ull << lane) - 1ull;
    if (!mA) klist[off + __popcll(balA & below)] = kA;
    if (!mB) klist[off + __popcll(balA) + __popcll(balB & below)] = kB;
    barrier_lgkm();

    // ---- score pass: balanced dense K stream over compacted keys ----
    {
        int key = (w < nun) ? klist[w] : 0;
        for (int slot = w; slot < nun; slot += 16) {
            const int nslot = slot + 16;
            const int nkey = (nslot < nun) ? klist[nslot] : 0;  // prefetch
            const float* kk = kb + (size_t)key * EMBD;
            const float4 ka = ld4(kk);
            const float4 kc = ld4(kk + 4);
            float sv = qa.x * ka.x + qa.y * ka.y + qa.z * ka.z + qa.w * ka.w
                     + qc.x * kc.x + qc.y * kc.y + qc.z * kc.z + qc.w * kc.w;
            sv += __shfl_xor(sv, 1, 8);
            sv += __shfl_xor(sv, 2, 8);
            sv += __shfl_xor(sv, 4, 8);
            if (sub == 0) sc[hq][key] = sv * 0.125f;   // 1/sqrt(64)
            key = nkey;
        }
    }

    // softmax thread mapping: 2 waves per head; tl = 0..127 within head
    const int hh = w >> 1;
    const int tl = ((w & 1) << 6) | lane;

    barrier_lgkm();   // scores visible

    // ---- block max per head (masked entries are -1e30, never win) ----
    float lm = -INFINITY;
    #pragma unroll
    for (int j = 0; j < 16; ++j) lm = fmaxf(lm, sc[hh][j * 128 + tl]);
    #pragma unroll
    for (int offr = 32; offr >= 1; offr >>= 1)
        lm = fmaxf(lm, __shfl_xor(lm, offr, 64));
    if (lane == 0) redm[w] = lm;
    barrier_lgkm();
    const float m = fmaxf(redm[hh * 2], redm[hh * 2 + 1]);

    // ---- exp + denom (masked: exp(-1e30 - m) == 0, branchless) ----
    float ls = 0.f;
    #pragma unroll
    for (int j = 0; j < 16; ++j) {
        const int kk2 = j * 128 + tl;
        const float p = __expf(sc[hh][kk2] - m);
        sc[hh][kk2] = p;
        ls += p;
    }
    #pragma unroll
    for (int offr = 32; offr >= 1; offr >>= 1) ls += __shfl_xor(ls, offr, 64);
    if (lane == 0) redl[w] = ls;
    barrier_lgkm();   // p values + partial denoms visible

    // ---- V pass: balanced dense V stream over compacted keys ----
    float4 a0 = {0.f, 0.f, 0.f, 0.f};
    float4 a1 = {0.f, 0.f, 0.f, 0.f};
    {
        int key = (w < nun) ? klist[w] : 0;
        for (int slot = w; slot < nun; slot += 16) {
            const int nslot = slot + 16;
            const int nkey = (nslot < nun) ? klist[nslot] : 0;  // prefetch
            const float* vv = vb + (size_t)key * EMBD;
            const float4 va = ld4(vv);
            const float4 vc = ld4(vv + 4);
            const float p = sc[hq][key];    // distinct banks across heads
            a0.x = fmaf(p, va.x, a0.x); a0.y = fmaf(p, va.y, a0.y);
            a0.z = fmaf(p, va.z, a0.z); a0.w = fmaf(p, va.w, a0.w);
            a1.x = fmaf(p, vc.x, a1.x); a1.y = fmaf(p, vc.y, a1.y);
            a1.z = fmaf(p, vc.z, a1.z); a1.w = fmaf(p, vc.w, a1.w);
            key = nkey;
        }
    }

    barrier_lgkm();   // all sc reads done -> safe to reuse as acc buffer
    float* accb = &sc[0][0];
    *reinterpret_cast<float4*>(&accb[w * ACP + lane * 8])     = a0;
    *reinterpret_cast<float4*>(&accb[w * ACP + lane * 8 + 4]) = a1;
    barrier_lgkm();

    if (t < EMBD) {
        float s = 0.f;
        #pragma unroll
        for (int ww = 0; ww < 16; ++ww) s += accb[ww * ACP + t];
        const int h = t >> 6;
        const float den = redl[h * 2] + redl[h * 2 + 1];
        merged[(size_t)b * EMBD + t] = s / den;
    }
}

// Tiled projection: block = 8 batches x 64 j's (W_o stays L2-resident).
__global__ __launch_bounds__(256) void proj_kernel_split(
    const float* __restrict__ merged,
    const float* __restrict__ Wo,
    float* __restrict__ out)
{
    const int bt = blockIdx.x >> 3;
    const int jt = blockIdx.x & 7;
    const int t  = threadIdx.x;
    __shared__ float4 mrow[8 * 128];
    #pragma unroll
    for (int k = 0; k < 4; ++k) {
        const int idx = k * 256 + t;
        mrow[idx] = reinterpret_cast<const float4*>(
            merged + (size_t)bt * 8 * EMBD)[idx];
    }
    __syncthreads();

    const int j    = jt * 64 + (t & 63);
    const int brel = t >> 6;
    const float4* wrow = reinterpret_cast<const float4*>(Wo + (size_t)j * EMBD);
    const float4* m0 = &mrow[brel * 128];
    const float4* m1 = &mrow[(brel + 4) * 128];
    float s0 = 0.f, s1 = 0.f;
    #pragma unroll 4
    for (int i = 0; i < 128; ++i) {
        const float4 wv = wrow[i];
        const float4 x0 = m0[i];
        const float4 x1 = m1[i];
        s0 += wv.x * x0.x + wv.y * x0.y + wv.z * x0.z + wv.w * x0.w;
        s1 += wv.x * x1.x + wv.y * x1.y + wv.z * x1.z + wv.w * x1.w;
    }
    out[(size_t)(bt * 8 + brel) * EMBD + j] = s0;
    out[(size_t)(bt * 8 + brel + 4) * EMBD + j] = s1;
}

// In-place-safe fallback (merged aliases out).
__global__ __launch_bounds__(256) void proj_kernel_inplace(
    const float* __restrict__ merged,
    const float* __restrict__ Wo,
    float* __restrict__ out)
{
    const int b = blockIdx.x;
    const int t = threadIdx.x;
    __shared__ float mrow[EMBD];
    *reinterpret_cast<float2*>(&mrow[t * 2]) =
        *reinterpret_cast<const float2*>(&merged[(size_t)b * EMBD + t * 2]);
    __syncthreads();

    const float4* mv = reinterpret_cast<const float4*>(mrow);
    #pragma unroll
    for (int half = 0; half < 2; ++half) {
        const int j = t + half * 256;
        const float4* wrow = reinterpret_cast<const float4*>(Wo + (size_t)j * EMBD);
        float s = 0.f;
        #pragma unroll 4
        for (int i = 0; i < EMBD / 4; ++i) {
            const float4 wv = wrow[i];
            const float4 qv = mv[i];
            s += wv.x * qv.x + wv.y * qv.y + wv.z * qv.z + wv.w * qv.w;
        }
        out[(size_t)b * EMBD + j] = s;
    }
}

extern "C" void kernel_launch(void* const* d_in, const int* in_sizes, int n_in,
                              void* d_out, int out_size, void* d_ws, size_t ws_size,
                              hipStream_t stream) {
    const float* q    = (const float*)d_in[0];
    const float* kptr = (const float*)d_in[1];
    const float* vptr = (const float*)d_in[2];
    const float* Wo   = (const float*)d_in[3];
    const int*   mask = (const int*)d_in[4];
    float* out = (float*)d_out;

    float* merged = (ws_size >= (size_t)NB * EMBD * sizeof(float))
                        ? (float*)d_ws : out;

    attn_kernel<<<NB, 1024, 0, stream>>>(q, kptr, vptr, mask, merged);
    if (merged != out)
        proj_kernel_split<<<NB, 256, 0, stream>>>(merged, Wo, out);
    else
        proj_kernel_inplace<<<NB, 256, 0, stream>>>(merged, Wo, out);
}